// Round 1
// baseline (443.512 us; speedup 1.0000x reference)
//
#include <hip/hip_runtime.h>
#include <hip/hip_bf16.h>

// Problem constants (fixed by reference): B=4, L=4096, R=8, DV=64
#define BB  4
#define LL  4096
#define RR  8
#define DVV 64

typedef __bf16 bf16x8 __attribute__((ext_vector_type(8)));
typedef float  f32x4  __attribute__((ext_vector_type(4)));

// ---------------------------------------------------------------------------
// Pre-kernel: v[b][m][d] fp32 -> vT[b][d][m] bf16 (MFMA B-operand wants
// N-major/K-contiguous, i.e. v^T); mask int -> maskf float 0/1.
// 1M elements, coalesced reads; scattered 2B writes merge in L2 (vT = 2MB).
// ---------------------------------------------------------------------------
__global__ __launch_bounds__(256) void prep_kernel(const float* __restrict__ v,
                                                   const int* __restrict__ mask,
                                                   __bf16* __restrict__ vT,
                                                   float* __restrict__ maskf) {
  const int idx = blockIdx.x * 256 + threadIdx.x;   // exactly B*L*DV threads
  const int d = idx & 63;
  const int m = (idx >> 6) & 4095;
  const int b = idx >> 18;
  vT[((b * DVV + d) << 12) | m] = (__bf16)v[idx];
  if (idx < BB * LL) maskf[idx] = mask[idx] ? 1.0f : 0.0f;
}

// Compute 8 masked-exp score values for this lane at column block m0..m0+7.
// scores[row][m] = sum_r ra1[row][r] * ra2[r][m];  e = exp(s) * maskf[m]
// No max-subtraction needed: |s| <= ~17 -> exp safely in fp32 range.
__device__ __forceinline__ void score_exp(const float* __restrict__ ra2b,
                                          const float* __restrict__ mfb,
                                          const float* __restrict__ ar,
                                          const int m0, float* __restrict__ e) {
  float s[8];
#pragma unroll
  for (int j = 0; j < 8; ++j) s[j] = 0.f;
#pragma unroll
  for (int r = 0; r < RR; ++r) {
    const f32x4 b0 = *(const f32x4*)(ra2b + r * LL + m0);
    const f32x4 b1 = *(const f32x4*)(ra2b + r * LL + m0 + 4);
#pragma unroll
    for (int j = 0; j < 4; ++j) {
      s[j]     = fmaf(ar[r], b0[j], s[j]);
      s[4 + j] = fmaf(ar[r], b1[j], s[4 + j]);
    }
  }
  const f32x4 mf0 = *(const f32x4*)(mfb + m0);
  const f32x4 mf1 = *(const f32x4*)(mfb + m0 + 4);
#pragma unroll
  for (int j = 0; j < 4; ++j) {
    e[j]     = __expf(s[j]) * mf0[j];
    e[4 + j] = __expf(s[4 + j]) * mf1[j];
  }
}

// ---------------------------------------------------------------------------
// Main kernel: grid = B*L/16 workgroups (1024), 256 threads (4 waves).
// WG owns (b, 16-row block). Each wave owns a 1024-wide m-chunk.
// Lane -> (row = lane&15, kgroup = lane>>4) matches MFMA A-frag layout:
//   A[m=lane&15][k=(lane>>4)*8+j]  -> p computed directly in-frag.
// Pass 1: rowsum of e over own chunk (shfl + LDS cross-wave reduce).
// Pass 2: recompute e, p = e/rowsum -> write attn (fp32, nontemporal),
//         MFMA p(bf16) x vT(bf16) accumulate O; cross-wave LDS reduce of O.
// ---------------------------------------------------------------------------
__global__ __launch_bounds__(256, 4) void attn_main(
    const float* __restrict__ ra1, const float* __restrict__ ra2,
    const __bf16* __restrict__ vT, const float* __restrict__ maskf,
    float* __restrict__ out, float* __restrict__ attn) {
  const int wg   = blockIdx.x;          // 0..1023
  const int b    = wg >> 8;             // 256 row-blocks per batch
  const int row0 = (wg & 255) << 4;     // 16 rows per WG
  const int tid  = threadIdx.x;
  const int wave = tid >> 6;
  const int lane = tid & 63;
  const int lrow = lane & 15;
  const int k0   = (lane >> 4) << 3;    // 0,8,16,24
  const int row  = row0 + lrow;

  __shared__ float red[4][16];
  __shared__ float osum[4][16][DVV];    // 16 KB

  // ra1[b][row][0..7] -> registers (reused 512 times)
  const float* a_ptr = ra1 + (size_t)(b * LL + row) * RR;
  float ar[RR];
  {
    const f32x4 a0 = *(const f32x4*)(a_ptr);
    const f32x4 a1 = *(const f32x4*)(a_ptr + 4);
#pragma unroll
    for (int r = 0; r < 4; ++r) { ar[r] = a0[r]; ar[4 + r] = a1[r]; }
  }

  const int    mchunk = wave << 10;     // 1024 columns per wave
  const float* ra2b   = ra2 + (size_t)b * RR * LL;
  const float* mfb    = maskf + (size_t)b * LL;

  // ---- Pass 1: row sums of exp(s)*mask ----
  float rsum = 0.f;
#pragma unroll 1
  for (int t = 0; t < 32; ++t) {
    const int m0 = mchunk + (t << 5) + k0;
    float e[8];
    score_exp(ra2b, mfb, ar, m0, e);
#pragma unroll
    for (int j = 0; j < 8; ++j) rsum += e[j];
  }
  // reduce the 4 k-groups that share a row
  rsum += __shfl_xor(rsum, 16, 64);
  rsum += __shfl_xor(rsum, 32, 64);
  if (lane < 16) red[wave][lrow] = rsum;
  __syncthreads();
  const float rinv =
      1.0f / (red[0][lrow] + red[1][lrow] + red[2][lrow] + red[3][lrow]);

  // ---- Pass 2: normalized attn write + PV via bf16 MFMA ----
  f32x4 acc[4];
#pragma unroll
  for (int g = 0; g < 4; ++g)
#pragma unroll
    for (int i = 0; i < 4; ++i) acc[g][i] = 0.f;

  float*        attn_row = attn + (size_t)(b * LL + row) * LL;
  const __bf16* vTb      = vT + (size_t)b * DVV * LL;

#pragma unroll 1
  for (int t = 0; t < 32; ++t) {
    const int m0 = mchunk + (t << 5) + k0;
    float e[8];
    score_exp(ra2b, mfb, ar, m0, e);

    float p[8];
#pragma unroll
    for (int j = 0; j < 8; ++j) p[j] = e[j] * rinv;

    // attn store: fp32, streaming (bypass-cache hint)
    f32x4 st0, st1;
#pragma unroll
    for (int j = 0; j < 4; ++j) { st0[j] = p[j]; st1[j] = p[4 + j]; }
    __builtin_nontemporal_store(st0, (f32x4*)(attn_row + m0));
    __builtin_nontemporal_store(st1, (f32x4*)(attn_row + m0 + 4));

    // A-fragment: p already lives at (row=lane&15, k=k0+j)
    bf16x8 af;
#pragma unroll
    for (int j = 0; j < 8; ++j) af[j] = (__bf16)p[j];

    // B-fragments from vT: lane reads vT[b][g*16+lrow][m0..m0+7] (16B)
#pragma unroll
    for (int g = 0; g < 4; ++g) {
      const bf16x8 bf =
          *(const bf16x8*)(vTb + ((size_t)(g * 16 + lrow) << 12) + m0);
      acc[g] = __builtin_amdgcn_mfma_f32_16x16x32_bf16(af, bf, acc[g], 0, 0, 0);
    }
  }

  // ---- Epilogue: cross-wave O reduction ----
  // C/D layout: row=(lane>>4)*4+i, col=g*16+(lane&15)
#pragma unroll
  for (int g = 0; g < 4; ++g)
#pragma unroll
    for (int i = 0; i < 4; ++i)
      osum[wave][(lane >> 4) * 4 + i][g * 16 + lrow] = acc[g][i];
  __syncthreads();

  {
    const int orow = tid >> 4;          // 0..15
    const int d    = (tid & 15) << 2;   // 0,4,..,60
    const f32x4 r0 = *(const f32x4*)&osum[0][orow][d];
    const f32x4 r1 = *(const f32x4*)&osum[1][orow][d];
    const f32x4 r2 = *(const f32x4*)&osum[2][orow][d];
    const f32x4 r3 = *(const f32x4*)&osum[3][orow][d];
    f32x4 o;
#pragma unroll
    for (int i = 0; i < 4; ++i) o[i] = (r0[i] + r1[i]) + (r2[i] + r3[i]);
    *(f32x4*)(out + (size_t)(b * LL + row0 + orow) * DVV + d) = o;
  }
}

extern "C" void kernel_launch(void* const* d_in, const int* in_sizes, int n_in,
                              void* d_out, int out_size, void* d_ws,
                              size_t ws_size, hipStream_t stream) {
  (void)in_sizes; (void)n_in; (void)out_size; (void)ws_size;
  const float* v    = (const float*)d_in[0];
  const int*   mask = (const int*)d_in[1];
  const float* ra1  = (const float*)d_in[2];
  const float* ra2  = (const float*)d_in[3];
  // d_in[4] = len_q, always 4096 (shapes fixed) -> constants above

  float* out  = (float*)d_out;
  float* attn = out + (size_t)BB * LL * DVV;   // outputs concatenated

  __bf16* vT    = (__bf16*)d_ws;                                   // 2 MB
  float*  maskf = (float*)((char*)d_ws + (size_t)BB * DVV * LL * 2); // 64 KB

  hipLaunchKernelGGL(prep_kernel, dim3(BB * LL * DVV / 256), dim3(256), 0,
                     stream, v, mask, vT, maskf);
  hipLaunchKernelGGL(attn_main, dim3(BB * LL / 16), dim3(256), 0, stream, ra1,
                     ra2, vT, maskf, out, attn);
}

// Round 2
// 437.142 us; speedup vs baseline: 1.0146x; 1.0146x over previous
//
#include <hip/hip_runtime.h>
#include <hip/hip_bf16.h>

// Problem constants (fixed by reference): B=4, L=4096, R=8, DV=64
#define BB  4
#define LL  4096
#define RR  8
#define DVV 64

typedef __bf16 bf16x8 __attribute__((ext_vector_type(8)));
typedef float  f32x4  __attribute__((ext_vector_type(4)));

// ---------------------------------------------------------------------------
// Pre-kernel: LDS-tiled transpose v[b][m][d] fp32 -> vT[b][d][m] bf16, plus
// mask int -> maskf float. Grid = B * L/64 = 256 blocks of 256 threads; each
// block transposes a 64(m) x 64(d) tile. Coalesced 4B reads, coalesced 16B
// writes (8 rows x 128B per wave). LDS row stride 72 keeps 16B reads aligned.
// ---------------------------------------------------------------------------
__global__ __launch_bounds__(256) void prep_kernel(const float* __restrict__ v,
                                                   const int* __restrict__ mask,
                                                   __bf16* __restrict__ vT,
                                                   float* __restrict__ maskf) {
  __shared__ __bf16 tl[64][72];
  const int blk = blockIdx.x;
  const int b   = blk >> 6;           // 64 tiles per batch
  const int m0  = (blk & 63) << 6;
  const int tid = threadIdx.x;
  const float* vb = v + (((size_t)(b * LL + m0)) << 6);  // [64 m][64 d]
#pragma unroll
  for (int i = 0; i < 16; ++i) {
    const int idx = (i << 8) + tid;   // 0..4095: m = idx>>6, d = idx&63
    tl[idx & 63][idx >> 6] = (__bf16)vb[idx];
  }
  const int g = blk * 256 + tid;      // 65536 threads >= B*L
  if (g < BB * LL) maskf[g] = mask[g] ? 1.0f : 0.0f;
  __syncthreads();
#pragma unroll
  for (int i = 0; i < 2; ++i) {
    const int flat = (i << 8) + tid;  // 0..511: d = flat>>3, c = (flat&7)*8
    const int d = flat >> 3, c = (flat & 7) << 3;
    *(bf16x8*)(vT + (((size_t)(b * DVV + d)) << 12) + m0 + c) =
        *(const bf16x8*)&tl[d][c];
  }
}

// 8 masked-exp score values for this lane at columns m0..m0+7.
// No max-subtraction needed: |s| <= ~17 -> exp safely in fp32 range.
__device__ __forceinline__ void score_exp(const float* __restrict__ ra2b,
                                          const float* __restrict__ mfb,
                                          const float* __restrict__ ar,
                                          const int m0, float* __restrict__ e) {
  float s[8];
#pragma unroll
  for (int j = 0; j < 8; ++j) s[j] = 0.f;
#pragma unroll
  for (int r = 0; r < RR; ++r) {
    const f32x4 b0 = *(const f32x4*)(ra2b + r * LL + m0);
    const f32x4 b1 = *(const f32x4*)(ra2b + r * LL + m0 + 4);
#pragma unroll
    for (int j = 0; j < 4; ++j) {
      s[j]     = fmaf(ar[r], b0[j], s[j]);
      s[4 + j] = fmaf(ar[r], b1[j], s[4 + j]);
    }
  }
  const f32x4 mf0 = *(const f32x4*)(mfb + m0);
  const f32x4 mf1 = *(const f32x4*)(mfb + m0 + 4);
#pragma unroll
  for (int j = 0; j < 4; ++j) {
    e[j]     = __expf(s[j]) * mf0[j];
    e[4 + j] = __expf(s[4 + j]) * mf1[j];
  }
}

// ---------------------------------------------------------------------------
// Main kernel: grid = B*L/16 = 1024 WGs, 512 threads (8 waves) -> 4 blocks/CU
// x 8 waves = 32 waves/CU = 100% occupancy (R1 was grid-capped at 16/CU).
// WG owns (b, 16-row block); wave owns a 512-wide m-chunk (16 t-iters).
// Lane -> (row = lane&15, kgroup = lane>>4) == MFMA A-frag layout, so p is
// computed directly in-fragment. Plain (cached) stores: L2 ack is fast, so
// the in-order vmcnt coupling between stores and next-iter loads is cheap
// (R1's nontemporal stores made every load-wait a slow store drain).
// ---------------------------------------------------------------------------
__global__ __launch_bounds__(512, 8) void attn_main(
    const float* __restrict__ ra1, const float* __restrict__ ra2,
    const __bf16* __restrict__ vT, const float* __restrict__ maskf,
    float* __restrict__ out, float* __restrict__ attn) {
  const int wg   = blockIdx.x;          // 0..1023
  const int b    = wg >> 8;             // 256 row-blocks per batch
  const int row0 = (wg & 255) << 4;     // 16 rows per WG
  const int tid  = threadIdx.x;
  const int wave = tid >> 6;            // 0..7
  const int lane = tid & 63;
  const int lrow = lane & 15;
  const int k0   = (lane >> 4) << 3;    // 0,8,16,24
  const int row  = row0 + lrow;

  __shared__ float red[8][16];
  __shared__ float osum[8][16][DVV];    // 32 KB

  // ra1[b][row][0..7] -> registers (reused 512 times per pass)
  const float* a_ptr = ra1 + (size_t)(b * LL + row) * RR;
  float ar[RR];
  {
    const f32x4 a0 = *(const f32x4*)(a_ptr);
    const f32x4 a1 = *(const f32x4*)(a_ptr + 4);
#pragma unroll
    for (int r = 0; r < 4; ++r) { ar[r] = a0[r]; ar[4 + r] = a1[r]; }
  }

  const int    mchunk = wave << 9;      // 512 columns per wave
  const float* ra2b   = ra2 + (size_t)b * RR * LL;
  const float* mfb    = maskf + (size_t)b * LL;

  // ---- Pass 1: row sums of exp(s)*mask ----
  float rsum = 0.f;
#pragma unroll 1
  for (int t = 0; t < 16; ++t) {
    const int m0 = mchunk + (t << 5) + k0;
    float e[8];
    score_exp(ra2b, mfb, ar, m0, e);
#pragma unroll
    for (int j = 0; j < 8; ++j) rsum += e[j];
  }
  // reduce the 4 k-groups that share a row, then across 8 waves via LDS
  rsum += __shfl_xor(rsum, 16, 64);
  rsum += __shfl_xor(rsum, 32, 64);
  if (lane < 16) red[wave][lrow] = rsum;
  __syncthreads();
  float rtot = 0.f;
#pragma unroll
  for (int w = 0; w < 8; ++w) rtot += red[w][lrow];
  const float rinv = 1.0f / rtot;

  // ---- Pass 2: normalized attn write + PV via bf16 MFMA ----
  f32x4 acc[4];
#pragma unroll
  for (int g = 0; g < 4; ++g)
#pragma unroll
    for (int i = 0; i < 4; ++i) acc[g][i] = 0.f;

  float*        attn_row = attn + (size_t)(b * LL + row) * LL;
  const __bf16* vTb      = vT + (size_t)b * DVV * LL;

#pragma unroll 1
  for (int t = 0; t < 16; ++t) {
    const int m0 = mchunk + (t << 5) + k0;
    float e[8];
    score_exp(ra2b, mfb, ar, m0, e);

#pragma unroll
    for (int j = 0; j < 8; ++j) e[j] *= rinv;   // p, in place

    // attn store: plain cached stores (write-combine + fast L2 ack)
    f32x4 st0, st1;
#pragma unroll
    for (int j = 0; j < 4; ++j) { st0[j] = e[j]; st1[j] = e[4 + j]; }
    *(f32x4*)(attn_row + m0)     = st0;
    *(f32x4*)(attn_row + m0 + 4) = st1;

    // A-fragment: p already lives at (row=lane&15, k=k0+j)
    bf16x8 af;
#pragma unroll
    for (int j = 0; j < 8; ++j) af[j] = (__bf16)e[j];

    // B-fragments from vT: lane reads vT[b][g*16+lrow][m0..m0+7] (16B)
#pragma unroll
    for (int g = 0; g < 4; ++g) {
      const bf16x8 bf =
          *(const bf16x8*)(vTb + ((size_t)(g * 16 + lrow) << 12) + m0);
      acc[g] = __builtin_amdgcn_mfma_f32_16x16x32_bf16(af, bf, acc[g], 0, 0, 0);
    }
  }

  // ---- Epilogue: cross-wave O reduction ----
  // C/D layout: row=(lane>>4)*4+i, col=g*16+(lane&15)
#pragma unroll
  for (int g = 0; g < 4; ++g)
#pragma unroll
    for (int i = 0; i < 4; ++i)
      osum[wave][(lane >> 4) * 4 + i][g * 16 + lrow] = acc[g][i];
  __syncthreads();

  if (tid < 256) {
    const int orow = tid >> 4;          // 0..15
    const int d    = (tid & 15) << 2;   // 0,4,..,60
    f32x4 o;
#pragma unroll
    for (int i = 0; i < 4; ++i) o[i] = 0.f;
#pragma unroll
    for (int w = 0; w < 8; ++w) {
      const f32x4 r = *(const f32x4*)&osum[w][orow][d];
#pragma unroll
      for (int i = 0; i < 4; ++i) o[i] += r[i];
    }
    *(f32x4*)(out + (size_t)(b * LL + row0 + orow) * DVV + d) = o;
  }
}

extern "C" void kernel_launch(void* const* d_in, const int* in_sizes, int n_in,
                              void* d_out, int out_size, void* d_ws,
                              size_t ws_size, hipStream_t stream) {
  (void)in_sizes; (void)n_in; (void)out_size; (void)ws_size;
  const float* v    = (const float*)d_in[0];
  const int*   mask = (const int*)d_in[1];
  const float* ra1  = (const float*)d_in[2];
  const float* ra2  = (const float*)d_in[3];
  // d_in[4] = len_q, always 4096 (shapes fixed) -> constants above

  float* out  = (float*)d_out;
  float* attn = out + (size_t)BB * LL * DVV;   // outputs concatenated

  __bf16* vT    = (__bf16*)d_ws;                                     // 2 MB
  float*  maskf = (float*)((char*)d_ws + (size_t)BB * DVV * LL * 2); // 64 KB

  hipLaunchKernelGGL(prep_kernel, dim3(BB * (LL / 64)), dim3(256), 0, stream,
                     v, mask, vT, maskf);
  hipLaunchKernelGGL(attn_main, dim3(BB * LL / 16), dim3(512), 0, stream, ra1,
                     ra2, vT, maskf, out, attn);
}

// Round 3
// 414.266 us; speedup vs baseline: 1.0706x; 1.0552x over previous
//
#include <hip/hip_runtime.h>
#include <hip/hip_bf16.h>

// Problem constants (fixed by reference): B=4, L=4096, R=8, DV=64
#define BB  4
#define LL  4096
#define RR  8
#define DVV 64
#define RA2S 4112   // padded ra2 row stride (floats): 16448 B = 257 lines -> +1 L1 set/row

typedef __bf16 bf16x8 __attribute__((ext_vector_type(8)));
typedef float  f32x4  __attribute__((ext_vector_type(4)));

// ---------------------------------------------------------------------------
// Pre-kernel (256 blocks x 256 thr):
//  * v[b][m][d] fp32 -> vF fragment-linear bf16: for each (b, 32-col block c,
//    g), 64 lanes' MFMA B-fragments stored contiguously (lane*16B). Kills the
//    8KB-stride 16-way scatter of the old vT load (all-same-L1-set misses).
//  * ra2 -> ra2p padded copy (stride 4112) so the 8 r-rows stop aliasing to
//    one L1 set (16KB stride before).
//  * mask int -> maskf float.
// ---------------------------------------------------------------------------
__global__ __launch_bounds__(256) void prep_kernel(
    const float* __restrict__ v, const int* __restrict__ mask,
    const float* __restrict__ ra2, __bf16* __restrict__ vF,
    float* __restrict__ ra2p, float* __restrict__ maskf) {
  __shared__ __bf16 tl[64][72];
  const int blk = blockIdx.x;         // 256 blocks
  const int b   = blk >> 6;           // 64 tiles per batch
  const int m0  = (blk & 63) << 6;
  const int tid = threadIdx.x;

  // load+transpose 64(m) x 64(d) tile to LDS [d][m]
  const float* vb = v + (((size_t)(b * LL + m0)) << 6);
#pragma unroll
  for (int i = 0; i < 16; ++i) {
    const int idx = (i << 8) + tid;   // m = idx>>6, d = idx&63
    tl[idx & 63][idx >> 6] = (__bf16)vb[idx];
  }

  const int g = blk * 256 + tid;      // 0..65535
  if (g < BB * LL) maskf[g] = mask[g] ? 1.0f : 0.0f;
#pragma unroll
  for (int i = 0; i < 2; ++i) {       // padded ra2 copy: 131072 elements
    const int e  = g + (i << 16);
    const int bb = e >> 15;           // / (R*L)
    const int r  = (e >> 12) & 7;
    const int m  = e & 4095;
    ra2p[(size_t)(bb * RR + r) * RA2S + m] = ra2[e];
  }
  __syncthreads();

  // vF: unit u in {0..7} -> (cb = u>>2, gg = u&3); lane l holds
  // V-row d = gg*16 + (l&15), cols cb*32 + (l>>4)*8 .. +8  (16B)
  const int wv = tid >> 6, ln = tid & 63;
#pragma unroll
  for (int i = 0; i < 2; ++i) {
    const int u  = wv + (i << 2);
    const int cb = u >> 2, gg = u & 3;
    const int d  = gg * 16 + (ln & 15);
    const int c  = cb * 32 + ((ln >> 4) << 3);
    const size_t unit = ((size_t)(b * 128 + (m0 >> 5) + cb) << 2) + gg;
    *(bf16x8*)(vF + (unit << 9) + (ln << 3)) = *(const bf16x8*)&tl[d][c];
  }
}

// 8 masked-exp score values for this lane at columns m0..m0+7 (padded ra2).
// No max-subtraction needed: |s| <= ~17 -> exp safely in fp32 range.
__device__ __forceinline__ void score_exp(const float* __restrict__ ra2b,
                                          const float* __restrict__ mfb,
                                          const float* __restrict__ ar,
                                          const int m0, float* __restrict__ e) {
  float s[8];
#pragma unroll
  for (int j = 0; j < 8; ++j) s[j] = 0.f;
#pragma unroll
  for (int r = 0; r < RR; ++r) {
    const f32x4 b0 = *(const f32x4*)(ra2b + r * RA2S + m0);
    const f32x4 b1 = *(const f32x4*)(ra2b + r * RA2S + m0 + 4);
#pragma unroll
    for (int j = 0; j < 4; ++j) {
      s[j]     = fmaf(ar[r], b0[j], s[j]);
      s[4 + j] = fmaf(ar[r], b1[j], s[4 + j]);
    }
  }
  const f32x4 mf0 = *(const f32x4*)(mfb + m0);
  const f32x4 mf1 = *(const f32x4*)(mfb + m0 + 4);
#pragma unroll
  for (int j = 0; j < 4; ++j) {
    e[j]     = __expf(s[j]) * mf0[j];
    e[4 + j] = __expf(s[4 + j]) * mf1[j];
  }
}

// ---------------------------------------------------------------------------
// Main kernel: 1024 WGs x 512 thr (8 waves) -> 32 waves/CU.
// WG owns (b, 16-row block); wave owns a 512-wide m-chunk (16 t-iters).
// Lane -> (row = lane&15, kgroup = lane>>4) == MFMA A-frag layout.
// vF makes the 4 B-fragment loads per iter one contiguous 4KB stream;
// ra2p's padded stride keeps the 8 score rows L1-resident.
// ---------------------------------------------------------------------------
__global__ __launch_bounds__(512, 8) void attn_main(
    const float* __restrict__ ra1, const float* __restrict__ ra2p,
    const __bf16* __restrict__ vF, const float* __restrict__ maskf,
    float* __restrict__ out, float* __restrict__ attn) {
  const int wg   = blockIdx.x;          // 0..1023
  const int b    = wg >> 8;             // 256 row-blocks per batch
  const int row0 = (wg & 255) << 4;     // 16 rows per WG
  const int tid  = threadIdx.x;
  const int wave = tid >> 6;            // 0..7
  const int lane = tid & 63;
  const int lrow = lane & 15;
  const int k0   = (lane >> 4) << 3;    // 0,8,16,24
  const int row  = row0 + lrow;

  __shared__ float red[8][16];
  __shared__ float osum[8][16][DVV];    // 32 KB

  const float* a_ptr = ra1 + (size_t)(b * LL + row) * RR;
  float ar[RR];
  {
    const f32x4 a0 = *(const f32x4*)(a_ptr);
    const f32x4 a1 = *(const f32x4*)(a_ptr + 4);
#pragma unroll
    for (int r = 0; r < 4; ++r) { ar[r] = a0[r]; ar[4 + r] = a1[r]; }
  }

  const int    mchunk = wave << 9;      // 512 columns per wave
  const float* ra2b   = ra2p + (size_t)b * RR * RA2S;
  const float* mfb    = maskf + (size_t)b * LL;

  // ---- Pass 1: row sums of exp(s)*mask ----
  float rsum = 0.f;
#pragma unroll 1
  for (int t = 0; t < 16; ++t) {
    const int m0 = mchunk + (t << 5) + k0;
    float e[8];
    score_exp(ra2b, mfb, ar, m0, e);
#pragma unroll
    for (int j = 0; j < 8; ++j) rsum += e[j];
  }
  rsum += __shfl_xor(rsum, 16, 64);
  rsum += __shfl_xor(rsum, 32, 64);
  if (lane < 16) red[wave][lrow] = rsum;
  __syncthreads();
  float rtot = 0.f;
#pragma unroll
  for (int w = 0; w < 8; ++w) rtot += red[w][lrow];
  const float rinv = 1.0f / rtot;

  // ---- Pass 2: normalized attn write + PV via bf16 MFMA ----
  f32x4 acc[4];
#pragma unroll
  for (int g = 0; g < 4; ++g)
#pragma unroll
    for (int i = 0; i < 4; ++i) acc[g][i] = 0.f;

  float*        attn_row = attn + (size_t)(b * LL + row) * LL;
  const __bf16* vFb      = vF + ((size_t)b << 18);   // b * 128*4*512

#pragma unroll 1
  for (int t = 0; t < 16; ++t) {
    const int m0 = mchunk + (t << 5) + k0;
    float e[8];
    score_exp(ra2b, mfb, ar, m0, e);

#pragma unroll
    for (int j = 0; j < 8; ++j) e[j] *= rinv;   // p, in place

    f32x4 st0, st1;
#pragma unroll
    for (int j = 0; j < 4; ++j) { st0[j] = e[j]; st1[j] = e[4 + j]; }
    *(f32x4*)(attn_row + m0)     = st0;
    *(f32x4*)(attn_row + m0 + 4) = st1;

    // A-fragment: p already lives at (row=lane&15, k=k0+j)
    bf16x8 af;
#pragma unroll
    for (int j = 0; j < 8; ++j) af[j] = (__bf16)e[j];

    // B-fragments: contiguous 4KB block for this iter, lane-linear
    const __bf16* vblk =
        vFb + ((size_t)(((mchunk >> 5) + t)) << 11) + (lane << 3);
#pragma unroll
    for (int g = 0; g < 4; ++g) {
      const bf16x8 bf = *(const bf16x8*)(vblk + (g << 9));
      acc[g] = __builtin_amdgcn_mfma_f32_16x16x32_bf16(af, bf, acc[g], 0, 0, 0);
    }
  }

  // ---- Epilogue: cross-wave O reduction ----
  // C/D layout: row=(lane>>4)*4+i, col=g*16+(lane&15)
#pragma unroll
  for (int g = 0; g < 4; ++g)
#pragma unroll
    for (int i = 0; i < 4; ++i)
      osum[wave][(lane >> 4) * 4 + i][g * 16 + lrow] = acc[g][i];
  __syncthreads();

  if (tid < 256) {
    const int orow = tid >> 4;          // 0..15
    const int d    = (tid & 15) << 2;   // 0,4,..,60
    f32x4 o;
#pragma unroll
    for (int i = 0; i < 4; ++i) o[i] = 0.f;
#pragma unroll
    for (int w = 0; w < 8; ++w) {
      const f32x4 r = *(const f32x4*)&osum[w][orow][d];
#pragma unroll
      for (int i = 0; i < 4; ++i) o[i] += r[i];
    }
    *(f32x4*)(out + (size_t)(b * LL + row0 + orow) * DVV + d) = o;
  }
}

extern "C" void kernel_launch(void* const* d_in, const int* in_sizes, int n_in,
                              void* d_out, int out_size, void* d_ws,
                              size_t ws_size, hipStream_t stream) {
  (void)in_sizes; (void)n_in; (void)out_size; (void)ws_size;
  const float* v    = (const float*)d_in[0];
  const int*   mask = (const int*)d_in[1];
  const float* ra1  = (const float*)d_in[2];
  const float* ra2  = (const float*)d_in[3];
  // d_in[4] = len_q, always 4096 (shapes fixed) -> constants above

  float* out  = (float*)d_out;
  float* attn = out + (size_t)BB * LL * DVV;   // outputs concatenated

  // ws layout (16B-aligned offsets): ra2p | maskf | vF
  float*  ra2p  = (float*)d_ws;                                  // 526336 B
  float*  maskf = (float*)((char*)d_ws + (size_t)BB * RR * RA2S * 4);
  __bf16* vF    = (__bf16*)((char*)d_ws + (size_t)BB * RR * RA2S * 4 +
                            (size_t)BB * LL * 4);                // 2 MB

  hipLaunchKernelGGL(prep_kernel, dim3(BB * (LL / 64)), dim3(256), 0, stream,
                     v, mask, ra2, vF, ra2p, maskf);
  hipLaunchKernelGGL(attn_main, dim3(BB * LL / 16), dim3(512), 0, stream, ra1,
                     ra2p, vF, maskf, out, attn);
}